// Round 4
// baseline (133.589 us; speedup 1.0000x reference)
//
#include <hip/hip_runtime.h>
#include <hip/hip_bf16.h>

// out[i] = sum_{j!=i} relu(Wd_i@x_j + (Ws_i-Wd_i)@x_i + b_i) * x_j + x_i, 3 steps.
// MFMA 16x16x32 f16 with UNSCALED 2-way f16 split: v = h + m, m = v - (f16)v.
// f16 precision is scale-invariant -> all split products share scale 1 and the
// whole edge sum CHAINS through the MFMA C-operand (no VALU combine):
//   Q = mfma(ah,bh, mfma(ah,bm, mfma(am,bh, mfma(am,bm, bias))))
//   E = mfma(ah,bh, mfma(ah,bm, mfma(am,bh, Q)))      (mm term ~2^-22, dropped)
// Weight residuals (~2.4e-5) are f16-subnormal: ~2^-20 rel weight precision vs
// ~2^-22 scaled — 100x below the ~1e-4 association noise of the fp32 baseline.
// R9 (=R8): 64.5us, Occ 36%, Mfma 28%, VALU 43%, conflicts 8.55M.
// R10 FAILED: (512,8) spills (FETCH 186MB). True reg need ~128/wave incl AGPR.
// R11: fragment-major LDS xsf/xgf -> conflicts 8.55M->1.18M, dur FLAT 63.8us.
//   => LDS pipe was NOT critical; latency/issue-bound at 4 waves/SIMD.
// R12: chained-MFMA accumulation (this file): -72 VALU/wave/step (-28%),
//   sender critical path MFMA->fmax->fmaf (was MFMA->fmaf->fmax->fmaf).
// Spill go/no-go: FETCH/WRITE must stay ~37/37 MB (R4/R6/R10 spills: 166-270).

#define NN 8
#define NSTEPS 3
#define BB 4
#define CC 32
#define HWSZ 9216
#define PX 16

typedef _Float16 f16x8 __attribute__((ext_vector_type(8)));
typedef _Float16 f16x4 __attribute__((ext_vector_type(4)));
typedef _Float16 f16x2 __attribute__((ext_vector_type(2)));
typedef float    f32x4 __attribute__((ext_vector_type(4)));
typedef float    f32x2 __attribute__((ext_vector_type(2)));

#define MFMA(A, B, C) __builtin_amdgcn_mfma_f32_16x16x32_f16((A), (B), (C), 0, 0, 0)

__device__ __forceinline__ void split2(float v, _Float16& h, _Float16& m) {
    h = (_Float16)v;
    m = (_Float16)(v - (float)h);   // unscaled residual
}

__global__ __launch_bounds__(512, 4)
void gcn3_f16w(const float* __restrict__ nodes,
               const float* __restrict__ we,
               const float* __restrict__ be,
               float* __restrict__ out) {
    // Fragment-major: slot [lane] holds exactly the 16B that lane consumes.
    // xsf[s][n][lane][e]: B-frag f16 pair; lane = (c>>3)*16 + pixel, e = c&7.
    // xgf[n][t][lane][k]: fp32 gate master; lane = ((c>>2)&3)*16 + pixel, k = c&3, t = c>>4.
    __shared__ _Float16 xsf[2][NN][64][8];   // 16384 B
    __shared__ float    xgf[NN][2][64][4];   // 16384 B (total 32768)

    const int tid  = threadIdx.x;
    const int wid  = tid >> 6;     // receiver node i (0..7), one per wave
    const int lane = tid & 63;
    const int col  = lane & 15;    // pixel (B n / C col); A row m
    const int quad = lane >> 4;    // 0..3

    // ---- resident A-frags for ONE receiver: Wd, (Ws-Wd); 2-way split ----
    f16x8 awd[2][2], awsd[2][2];   // [tile][split] = 32 VGPRs
    f32x4 bias[2];
    #pragma unroll
    for (int t = 0; t < 2; ++t) {
        const float* wp = we + (size_t)((wid * CC + 16 * t + col) * (2 * CC)) + quad * 8;
        f32x4 d0 = *(const f32x4*)wp;
        f32x4 d1 = *(const f32x4*)(wp + 4);
        f32x4 s0 = *(const f32x4*)(wp + CC);
        f32x4 s1 = *(const f32x4*)(wp + CC + 4);
        #pragma unroll
        for (int k = 0; k < 8; ++k) {
            float d = (k < 4) ? d0[k & 3] : d1[k & 3];
            float s = (k < 4) ? s0[k & 3] : s1[k & 3];
            _Float16 h, m;
            split2(d, h, m);
            awd[t][0][k] = h; awd[t][1][k] = m;
            split2(s - d, h, m);
            awsd[t][0][k] = h; awsd[t][1][k] = m;
        }
        #pragma unroll
        for (int k = 0; k < 4; ++k)
            bias[t][k] = be[wid * CC + 16 * t + quad * 4 + k];
    }

    const int q0  = blockIdx.x * PX;
    const int b   = q0 / HWSZ;
    const int hw0 = q0 - b * HWSZ;

    // ---- stage: 1024 f32x2 units over 512 threads (2 iters) ----
    #pragma unroll
    for (int kk = 0; kk < 2; ++kk) {
        int idx = tid + kk * 512;            // 1024 = 8n * 16c2 * 8p2
        int p2 = (idx & 7) * 2;
        int c2 = ((idx >> 3) & 15) * 2;
        int n  = idx >> 7;
        const float* gp = nodes + (size_t)((n * BB + b) * CC + c2) * HWSZ + hw0 + p2;
        f32x2 v0 = *(const f32x2*)gp;            // channel c2
        f32x2 v1 = *(const f32x2*)(gp + HWSZ);   // channel c2+1
        #pragma unroll
        for (int e = 0; e < 2; ++e) {
            int px = p2 + e;
            _Float16 h0, m0, h1, m1;
            split2(v0[e], h0, m0);
            split2(v1[e], h1, m1);
            // channels c2, c2+1 are adjacent elems of the same B-frag slot
            *(f16x2*)&xsf[0][n][(c2 >> 3) * 16 + px][c2 & 7] = f16x2{h0, h1};
            *(f16x2*)&xsf[1][n][(c2 >> 3) * 16 + px][c2 & 7] = f16x2{m0, m1};
            *(f32x2*)&xgf[n][c2 >> 4][((c2 >> 2) & 3) * 16 + px][c2 & 3] = f32x2{v0[e], v1[e]};
        }
    }
    __syncthreads();

    f32x4 msg[2];

    #pragma unroll 1
    for (int step = 0; step < NSTEPS; ++step) {
        // ---- Q = (Ws-Wd)_i @ x_i + b : full chain through C (0 VALU) ----
        f32x4 qf[2];
        {
            f16x8 bh = *(const f16x8*)&xsf[0][wid][lane][0];
            f16x8 bm = *(const f16x8*)&xsf[1][wid][lane][0];
            #pragma unroll
            for (int t = 0; t < 2; ++t) {
                f32x4 q = MFMA(awsd[t][1], bm, bias[t]);   // mm (+bias)
                q = MFMA(awsd[t][1], bh, q);               // mh
                q = MFMA(awsd[t][0], bm, q);               // hm
                qf[t] = MFMA(awsd[t][0], bh, q);           // hh
            }
        }

        #pragma unroll
        for (int t = 0; t < 2; ++t)
            msg[t] = f32x4{0.f, 0.f, 0.f, 0.f};

        // ---- sender loop: E = Wd x_j + Q, chained (hh, hm, mh) ----
        #pragma unroll
        for (int j = 0; j < NN; ++j) {
            f32x4 xgj[2];
            #pragma unroll
            for (int t = 0; t < 2; ++t)
                xgj[t] = *(const f32x4*)&xgf[j][t][lane][0];
            if (j == wid) {                  // wave-uniform: residual
                #pragma unroll
                for (int t = 0; t < 2; ++t)
                    #pragma unroll
                    for (int k = 0; k < 4; ++k)
                        msg[t][k] += xgj[t][k];
            } else {
                f16x8 bh = *(const f16x8*)&xsf[0][j][lane][0];
                f16x8 bm = *(const f16x8*)&xsf[1][j][lane][0];
                #pragma unroll
                for (int t = 0; t < 2; ++t) {
                    f32x4 e = MFMA(awd[t][1], bh, qf[t]);   // mh (+Q)
                    e = MFMA(awd[t][0], bm, e);             // hm
                    e = MFMA(awd[t][0], bh, e);             // hh
                    #pragma unroll
                    for (int k = 0; k < 4; ++k) {
                        float g = fmaxf(e[k], 0.f);
                        msg[t][k] = fmaf(g, xgj[t][k], msg[t][k]);
                    }
                }
            }
        }

        if (step < NSTEPS - 1) {
            __syncthreads();   // all reads of old x done
            #pragma unroll
            for (int t = 0; t < 2; ++t) {
                f16x4 h4, m4;
                #pragma unroll
                for (int k = 0; k < 4; ++k) {
                    _Float16 h, m;
                    split2(msg[t][k], h, m);
                    h4[k] = h; m4[k] = m;
                }
                // channel c = 16t + quad*4 + k  ->  xsf slot (c>>3)*16+col, elem c&7
                int lane2 = (2 * t + (quad >> 1)) * 16 + col;
                int e0    = (quad & 1) * 4;
                *(f16x4*)&xsf[0][wid][lane2][e0] = h4;
                *(f16x4*)&xsf[1][wid][lane2][e0] = m4;
                *(f32x4*)&xgf[wid][t][lane][0] = msg[t];   // linear: conflict-free
            }
            __syncthreads();   // new x visible
        }
    }

    // ---- epilogue: direct fragment stores (per (t,k): 16-lane x 4B = 64B segs) ----
    #pragma unroll
    for (int t = 0; t < 2; ++t)
        #pragma unroll
        for (int k = 0; k < 4; ++k)
            out[(size_t)((wid * BB + b) * CC + 16 * t + quad * 4 + k) * HWSZ + hw0 + col] = msg[t][k];
}

extern "C" void kernel_launch(void* const* d_in, const int* in_sizes, int n_in,
                              void* d_out, int out_size, void* d_ws, size_t ws_size,
                              hipStream_t stream) {
    const float* nodes  = (const float*)d_in[0];
    const float* W_edge = (const float*)d_in[1];
    const float* b_edge = (const float*)d_in[2];
    float* outp = (float*)d_out;

    dim3 grid((BB * HWSZ) / PX);   // 2304 blocks of 512
    dim3 block(512);
    gcn3_f16w<<<grid, block, 0, stream>>>(nodes, W_edge, b_edge, outp);
}